// Round 18
// baseline (315.788 us; speedup 1.0000x reference)
//
#include <hip/hip_runtime.h>

#define DEV static __device__ __forceinline__

typedef __attribute__((ext_vector_type(8))) short short8;
typedef __attribute__((ext_vector_type(4))) float f32x4;
typedef __attribute__((ext_vector_type(16))) float f32x16;
typedef __attribute__((ext_vector_type(2))) unsigned int uint2v;

DEV unsigned short f2bf(float f) {
    union { float f; unsigned int u; } v; v.f = f;
    unsigned int u = v.u;
    unsigned int r = (u + 0x7fffu + ((u >> 16) & 1u)) >> 16;
    return (unsigned short)r;
}
DEV float bf2f(unsigned short s) {
    union { unsigned int u; float f; } v; v.u = ((unsigned int)s) << 16;
    return v.f;
}

// v_cvt_pk_bf16_f32: low short = lo, high short = hi (no builtin on gfx950, m240)
DEV unsigned int cvtpk(float lo, float hi) {
    unsigned int r;
    asm("v_cvt_pk_bf16_f32 %0, %1, %2" : "=v"(r) : "v"(lo), "v"(hi));
    return r;
}

// 2^x on the transcendental pipe
DEV float vexp2(float x) {
    float r;
    asm("v_exp_f32 %0, %1" : "=v"(r) : "v"(x));
    return r;
}

// lane<32 <-> lane>=32 exchange on the VALU pipe (not LDS)
DEV float pl32_max(float v) {
    union { float f; unsigned u; } c; c.f = v;
    uint2v r = __builtin_amdgcn_permlane32_swap(c.u, c.u, false, false);
    union { unsigned u; float f; } a, b; a.u = r[0]; b.u = r[1];
    return fmaxf(a.f, b.f);
}
DEV float pl32_sum(float v) {
    union { float f; unsigned u; } c; c.f = v;
    uint2v r = __builtin_amdgcn_permlane32_swap(c.u, c.u, false, false);
    union { unsigned u; float f; } a, b; a.u = r[0]; b.u = r[1];
    return a.f + b.f;
}

// XOR-swizzled LDS pointer: tile row stride rs shorts (power of 2), byte ^= (row&7)<<4
DEV unsigned short* swp(unsigned short* base, int row, int col, int rs) {
    int a = ((row * rs + col) << 1) ^ ((row & 7) << 4);
    return (unsigned short*)((char*)base + a);
}

// barrier that does NOT drain vmcnt: LDS-write visibility only.
DEV void lds_barrier() {
    asm volatile("s_waitcnt lgkmcnt(0)" ::: "memory");
    __builtin_amdgcn_s_barrier();
}

// async global->LDS, 16B/lane (used by QKV GEMM staging)
DEV void gload16(const void* g, void* l) {
    __builtin_amdgcn_global_load_lds((const __attribute__((address_space(1))) void*)g,
                                     (__attribute__((address_space(3))) void*)l, 16, 0, 0);
}

// build a PV B-frag from 8 P values (validated r5-r17)
DEV short8 mk_pf(float v0, float v1, float v2, float v3,
                 float v4, float v5, float v6, float v7) {
    unsigned X0 = cvtpk(v0, v1);
    unsigned X1 = cvtpk(v2, v3);
    unsigned Y0 = cvtpk(v4, v5);
    unsigned Y1 = cvtpk(v6, v7);
    uint2v r0 = __builtin_amdgcn_permlane32_swap(X0, Y0, false, false);
    uint2v r1 = __builtin_amdgcn_permlane32_swap(X1, Y1, false, false);
    union { unsigned u[4]; short8 s; } uu;
    uu.u[0] = r0[0];
    uu.u[1] = r1[0];
    uu.u[2] = r0[1];
    uu.u[3] = r1[1];
    return uu.s;
}

// ---------------- kernel 1: transpose + fused weight conversion (r17-validated) -----
__global__ __launch_bounds__(256) void transpose_kernel(const float* __restrict__ x,
                                                        unsigned short* __restrict__ Xt,
                                                        const float* __restrict__ qkv_w,
                                                        const float* __restrict__ proj_w,
                                                        unsigned short* __restrict__ Wq,
                                                        unsigned short* __restrict__ Wp) {
    __shared__ unsigned char lt[64 * 128];
    int b  = blockIdx.z;
    int c0 = blockIdx.y * 64;
    int t0 = blockIdx.x * 64;
    int tid = threadIdx.x;

    {
        int gtid = (((int)blockIdx.z * 8 + (int)blockIdx.y) * 32 + (int)blockIdx.x) * 256 + tid;
        for (int j = gtid; j < 1536 * 512; j += 524288) Wq[j] = f2bf(qkv_w[j]);
        for (int j = gtid; j < 512 * 512;  j += 524288) Wp[j] = f2bf(proj_w[j]);
    }

    int tx = tid & 15, cy0 = tid >> 4;
    for (int p = 0; p < 4; ++p) {
        int cy = cy0 + p * 16;
        const float* src = &x[((size_t)(b * 512 + c0 + cy)) * 2048 + t0 + tx * 4];
        f32x4 v = *(const f32x4*)src;
        unsigned long long pk = (unsigned long long)f2bf(v[0])
                              | ((unsigned long long)f2bf(v[1]) << 16)
                              | ((unsigned long long)f2bf(v[2]) << 32)
                              | ((unsigned long long)f2bf(v[3]) << 48);
        int addr = (cy * 128 + tx * 8) ^ ((cy & 7) << 4);
        *(unsigned long long*)(lt + addr) = pk;
    }
    __syncthreads();
    int c16 = (tid & 3) * 16, tr = tid >> 2;
    unsigned short buf[16];
    for (int i = 0; i < 16; ++i) {
        int c = c16 + i;
        int addr = (c * 128 + tr * 2) ^ ((c & 7) << 4);
        buf[i] = *(unsigned short*)(lt + addr);
    }
    unsigned short* dst = &Xt[((size_t)(b * 2048 + t0 + tr)) * 512 + c0 + c16];
    *(short8*)dst       = *(short8*)&buf[0];
    *(short8*)(dst + 8) = *(short8*)&buf[8];
}

// ---------------- kernel 2: QKV GEMM v2 (TEMPLATED orient — mandatory) --------------
template <int ORIENT>
__global__ __launch_bounds__(256, 2) void gemm_qkv_kernel(
    const unsigned short* __restrict__ Wq,   // [1536][512] bf16
    const unsigned short* __restrict__ Xt,   // [b][2048][512] bf16
    const float* __restrict__ qkv_b,
    unsigned short* __restrict__ Qw,
    unsigned short* __restrict__ Kw,
    unsigned short* __restrict__ Vw) {
    __shared__ unsigned short As[2][128 * 64];
    __shared__ unsigned short Bs[2][128 * 64];
    int b  = blockIdx.z;
    int ot = (ORIENT == 0) ? blockIdx.y : (8 + blockIdx.y);
    int o0 = ot * 128, t0 = blockIdx.x * 128;
    int tid = threadIdx.x, lane = tid & 63, w = tid >> 6;
    int lr = lane >> 4, lc = lane & 15;
    int wr = (w >> 1) * 64, wc = (w & 1) * 64;
    f32x4 acc[4][4];
    for (int m = 0; m < 4; m++)
        for (int n = 0; n < 4; n++) acc[m][n] = (f32x4){0.f, 0.f, 0.f, 0.f};

    int r8 = lane >> 3, ck = lane & 7;
    int sc8 = (ck ^ r8) * 8;

    const unsigned short* Wbase = &Wq[(size_t)o0 * 512];
    const unsigned short* Xbase = &Xt[((size_t)(b * 2048) + t0) * 512];

    #define QKV_STAGE(buf, ks)                                                        \
        _Pragma("unroll")                                                             \
        for (int p = 0; p < 4; p++) {                                                 \
            int rowblk = (w * 4 + p) * 8;                                             \
            gload16(&Wbase[(size_t)(rowblk + r8) * 512 + (ks) * 64 + sc8],            \
                    &As[buf][rowblk * 64]);                                           \
            gload16(&Xbase[(size_t)(rowblk + r8) * 512 + (ks) * 64 + sc8],            \
                    &Bs[buf][rowblk * 64]);                                           \
        }

    QKV_STAGE(0, 0);
    asm volatile("s_waitcnt vmcnt(0)" ::: "memory");
    __builtin_amdgcn_s_barrier();
    for (int t = 0; t < 8; ++t) {
        int cur = t & 1;
        if (t < 7) { QKV_STAGE(cur ^ 1, t + 1); }
        unsigned short* Ab = (unsigned short*)As[cur];
        unsigned short* Bb = (unsigned short*)Bs[cur];
        #pragma unroll
        for (int kk = 0; kk < 64; kk += 32) {
            int kb = kk + lr * 8;
            short8 af[4], bfv[4];
            if (ORIENT == 0) {
                for (int m = 0; m < 4; m++) af[m]  = *(const short8*)swp(Bb, wr + m * 16 + lc, kb, 64);
                for (int n = 0; n < 4; n++) bfv[n] = *(const short8*)swp(Ab, wc + n * 16 + lc, kb, 64);
            } else {
                for (int m = 0; m < 4; m++) af[m]  = *(const short8*)swp(Ab, wr + m * 16 + lc, kb, 64);
                for (int n = 0; n < 4; n++) bfv[n] = *(const short8*)swp(Bb, wc + n * 16 + lc, kb, 64);
            }
            for (int m = 0; m < 4; m++)
                for (int n = 0; n < 4; n++)
                    acc[m][n] = __builtin_amdgcn_mfma_f32_16x16x32_bf16(af[m], bfv[n], acc[m][n], 0, 0, 0);
        }
        asm volatile("s_waitcnt vmcnt(0)" ::: "memory");
        __builtin_amdgcn_s_barrier();
    }
    const float scale_k = 0.29730177875068026f;            // 128^-0.25
    const float scale_q = 0.42891498953885586f;            // 128^-0.25 * log2(e)
    for (int m = 0; m < 4; m++)
        for (int n = 0; n < 4; n++)
            for (int r = 0; r < 4; r++) {
                int row = wr + m * 16 + lr * 4 + r;
                int col = wc + n * 16 + lc;
                float val = acc[m][n][r];
                if (ORIENT == 0) {
                    int t = t0 + row;
                    int o = o0 + col;
                    float sc = (o < 512) ? scale_q : scale_k;
                    val = (val + qkv_b[o]) * sc;
                    if (o < 512) {
                        int h = o >> 7, cc = o & 127;
                        Qw[((size_t)((b * 4 + h) * 2048 + t)) * 128 + cc] = f2bf(val);
                    } else {
                        int oo = o - 512;
                        int h = oo >> 7, cc = oo & 127;
                        Kw[((size_t)((b * 4 + h) * 2048 + t)) * 128 + cc] = f2bf(val);
                    }
                } else {
                    int o = o0 + row;
                    int t = t0 + col;
                    val += qkv_b[o];
                    int oo = o - 1024;
                    int h = oo >> 7, cc = oo & 127;
                    Vw[((size_t)((b * 4 + h) * 128 + cc)) * 2048 + t] = f2bf(val);
                }
            }
}

// ---------------- kernel 3: flash attention v12 — s-split(2), r10 per-wave state ----
// 1024 blocks = 4/CU = 16 waves/CU (2x TLP vs r10; q-work invariant broken by split).
// 256 thr = 4 waves x 32 q; KVBLK=32 -> LDS 32KB (K dbuf 2x8KB + V dbuf 2x8KB).
// Same reg-prefetch + non-draining lds_barrier, permlane softmax, defer-max, exp2.
// Exports normalized partial O + (m,l); combine kernel merges the two s-halves.
__global__ __launch_bounds__(256, 4) void attn_kernel(
    const unsigned short* __restrict__ Qw,   // [bh][2048][128]
    const unsigned short* __restrict__ Kw,   // [bh][2048][128]
    const unsigned short* __restrict__ Vw,   // [bh][128][2048]
    unsigned short* __restrict__ Op,         // [2][32][2048][128] normalized partial O
    float* __restrict__ Ml) {                // [2][32][2048][2]  (m, l)
    __shared__ unsigned short lds[16384];    // K dbuf 2x4096, V dbuf 2x4096 shorts
    int bid = blockIdx.x;
    int bh = bid & 31;                       // K/V stream shares bid%8 (XCD)
    int rest = bid >> 5;                     // 0..31
    int t0 = (rest & 15) * 128;
    int side = rest >> 4;                    // 0/1 : s-half
    int sbase = side * 1024;
    int tid = threadIdx.x, lane = tid & 63, w = tid >> 6;
    int l31 = lane & 31, hi = lane >> 5;
    int qrow = w * 32;

    const unsigned short* Kbase = &Kw[(size_t)bh * 2048 * 128];
    const unsigned short* Vbase = &Vw[(size_t)bh * 128 * 2048];

    short8 qf[8];
    #pragma unroll
    for (int st = 0; st < 8; st++)
        qf[st] = *(const short8*)&Qw[((size_t)bh * 2048 + t0 + qrow + l31) * 128 + st * 16 + hi * 8];

    f32x16 oacc[4];
    #pragma unroll
    for (int ct = 0; ct < 4; ct++)
        #pragma unroll
        for (int i = 0; i < 16; i++) oacc[ct][i] = 0.f;
    float mst = -1e30f, lst = 0.f;

    // staging: K tile [32 s][128 ch]: rows kr + p*16; V tile [128 c][32 s]: rows vr + p*64
    int kr = tid >> 4, ko = (tid & 15) * 8;
    int vr = tid >> 2, vo = (tid & 3) * 8;

    short8 kreg[2], vreg[2];
    #pragma unroll
    for (int p = 0; p < 2; p++)
        kreg[p] = *(const short8*)&Kbase[(size_t)(sbase + kr + p * 16) * 128 + ko];
    #pragma unroll
    for (int p = 0; p < 2; p++)
        vreg[p] = *(const short8*)&Vbase[(size_t)(vr + p * 64) * 2048 + sbase + vo];

    for (int it = 0; it < 32; ++it) {
        int cur = it & 1;
        unsigned short* Kb = lds + cur * 4096;          // [32 s][128 ch] swz
        unsigned short* Vb = lds + 8192 + cur * 4096;   // [128 c][32 s] swz
        #pragma unroll
        for (int p = 0; p < 2; p++) *(short8*)swp(Kb, kr + p * 16, ko, 128) = kreg[p];
        #pragma unroll
        for (int p = 0; p < 2; p++) *(short8*)swp(Vb, vr + p * 64, vo, 32) = vreg[p];
        if (it + 1 < 32) {
            int s1 = sbase + (it + 1) * 32;
            #pragma unroll
            for (int p = 0; p < 2; p++)
                kreg[p] = *(const short8*)&Kbase[(size_t)(s1 + kr + p * 16) * 128 + ko];
            #pragma unroll
            for (int p = 0; p < 2; p++)
                vreg[p] = *(const short8*)&Vbase[(size_t)(vr + p * 64) * 2048 + s1 + vo];
        }
        lds_barrier();   // prefetch stays in flight; LDS writes visible

        // S'[s][q] = K·Q^T (one 32-row s-block)
        f32x16 s0;
        #pragma unroll
        for (int i = 0; i < 16; i++) s0[i] = 0.f;
        __builtin_amdgcn_s_setprio(1);
        #pragma unroll
        for (int st = 0; st < 8; st++) {
            short8 k0 = *(const short8*)swp(Kb, l31, st * 16 + hi * 8, 128);
            s0 = __builtin_amdgcn_mfma_f32_32x32x16_bf16(k0, qf[st], s0, 0, 0, 0);
        }
        __builtin_amdgcn_s_setprio(0);

        // online softmax (exp2 domain), in-lane + permlane
        float m8[8];
        #pragma unroll
        for (int i = 0; i < 8; i++) m8[i] = fmaxf(s0[i], s0[i + 8]);
        #pragma unroll
        for (int sdt = 4; sdt > 0; sdt >>= 1)
            #pragma unroll
            for (int i = 0; i < 4; i++)
                if (i < sdt) m8[i] = fmaxf(m8[i], m8[i + sdt]);
        float mx = pl32_max(m8[0]);
        if (!__all(mx <= mst + 11.541560327111707f)) {   // 8 * log2(e)
            float mnew = fmaxf(mst, mx);
            float resc = vexp2(mst - mnew);
            mst = mnew;
            lst *= resc;
            #pragma unroll
            for (int ct = 0; ct < 4; ct++)
                #pragma unroll
                for (int i = 0; i < 16; i++) oacc[ct][i] *= resc;
        }
        float pe[16];
        #pragma unroll
        for (int i = 0; i < 16; i++) pe[i] = vexp2(s0[i] - mst);
        float a8[8];
        #pragma unroll
        for (int i = 0; i < 8; i++) a8[i] = pe[i] + pe[i + 8];
        #pragma unroll
        for (int sdt = 4; sdt > 0; sdt >>= 1)
            #pragma unroll
            for (int i = 0; i < 4; i++)
                if (i < sdt) a8[i] = a8[i] + a8[i + sdt];
        lst += pl32_sum(a8[0]);

        // PV B-frags (same pe[st*8+..] -> frag mapping as r10, st in {0,1})
        short8 pf[2];
        pf[0] = mk_pf(pe[0], pe[1], pe[2], pe[3], pe[4], pe[5], pe[6], pe[7]);
        pf[1] = mk_pf(pe[8], pe[9], pe[10], pe[11], pe[12], pe[13], pe[14], pe[15]);

        // O[c][q] += V·P
        __builtin_amdgcn_s_setprio(1);
        #pragma unroll
        for (int ct = 0; ct < 4; ct++)
            #pragma unroll
            for (int st = 0; st < 2; st++) {
                short8 va = *(const short8*)swp(Vb, ct * 32 + l31, st * 16 + hi * 8, 32);
                oacc[ct] = __builtin_amdgcn_mfma_f32_32x32x16_bf16(va, pf[st], oacc[ct], 0, 0, 0);
            }
        __builtin_amdgcn_s_setprio(0);
    }

    // epilogue: O/l -> per-wave LDS [32 q][128 c] -> coalesced Op; (m,l) -> Ml
    __syncthreads();
    unsigned short* ep = lds + w * 4096;
    float invl = 1.f / lst;
    #pragma unroll
    for (int ct = 0; ct < 4; ct++)
        #pragma unroll
        for (int i = 0; i < 8; i++) {
            int c = (2 * i & 3) + 8 * (i >> 1) + 4 * hi + 32 * ct;
            unsigned d = cvtpk(oacc[ct][2 * i] * invl, oacc[ct][2 * i + 1] * invl);
            *(unsigned*)swp(ep, l31, c, 128) = d;
        }
    asm volatile("" ::: "memory");
    int q = lane >> 1, hf = lane & 1;
    unsigned short* Opb = Op + ((size_t)(side * 32 + bh) * 2048 + t0 + qrow) * 128;
    float* Mlb = Ml + ((size_t)(side * 32 + bh) * 2048) * 2;
    #pragma unroll
    for (int p = 0; p < 8; p++) {
        short8 v = *(const short8*)swp(ep, q, hf * 64 + p * 8, 128);
        *(short8*)&Opb[(size_t)q * 128 + hf * 64 + p * 8] = v;
    }
    if (hi == 0) {
        Mlb[(size_t)(t0 + qrow + l31) * 2 + 0] = mst;
        Mlb[(size_t)(t0 + qrow + l31) * 2 + 1] = lst;
    }
}

// ---------------- kernel 3b: combine the two s-halves (r11-validated) ---------------
__global__ __launch_bounds__(256) void combine_kernel(
    const unsigned short* __restrict__ Op,   // [2][32][2048][128]
    const float* __restrict__ Ml,            // [2][32][2048][2]
    unsigned short* __restrict__ Aw) {       // [b][2048][512]
    int g = blockIdx.x * 256 + threadIdx.x;  // 1,048,576 chunks of 8
    int c8 = g & 15;
    int row = g >> 4;                        // bh*2048 + t
    int bh = row >> 11;
    int t  = row & 2047;
    const size_t SIDE = (size_t)32 * 2048 * 128;
    size_t o0 = (size_t)row * 128 + c8 * 8;
    float m0 = Ml[(size_t)row * 2], l0 = Ml[(size_t)row * 2 + 1];
    float m1 = Ml[((size_t)32 * 2048 + row) * 2], l1 = Ml[((size_t)32 * 2048 + row) * 2 + 1];
    float M = fmaxf(m0, m1);
    float w0 = vexp2(m0 - M) * l0;
    float w1 = vexp2(m1 - M) * l1;
    float inv = 1.f / (w0 + w1);
    w0 *= inv; w1 *= inv;
    short8 a = *(const short8*)&Op[o0];
    short8 b = *(const short8*)&Op[SIDE + o0];
    unsigned short outv[8];
    #pragma unroll
    for (int j = 0; j < 8; j++)
        outv[j] = f2bf(bf2f((unsigned short)a[j]) * w0 + bf2f((unsigned short)b[j]) * w1);
    int bq = bh >> 2, h = bh & 3;
    *(short8*)&Aw[((size_t)(bq * 2048) + t) * 512 + h * 128 + c8 * 8] = *(short8*)outv;
}

// ---------------- kernel 4: proj GEMM + bias + residual (dbuf + reg prefetch) -------
#define LP 72
__global__ __launch_bounds__(256, 2) void gemm_proj_kernel(
    const unsigned short* __restrict__ Wp,   // [512][512] bf16
    const unsigned short* __restrict__ Aw,   // [b][2048][512] bf16
    const float* __restrict__ proj_b,
    const float* __restrict__ x,             // [b][512][2048] f32
    float* __restrict__ out) {
    __shared__ unsigned short Ws[2][128][LP];
    __shared__ unsigned short Bs[2][128][LP];
    int b  = blockIdx.z;
    int o0 = blockIdx.y * 128, t0 = blockIdx.x * 128;
    int tid = threadIdx.x, lane = tid & 63, w = tid >> 6;
    int lr = lane >> 4, lc = lane & 15;
    int wr = (w >> 1) * 64, wc = (w & 1) * 64;
    f32x4 acc[4][4];
    for (int m = 0; m < 4; m++)
        for (int n = 0; n < 4; n++) acc[m][n] = (f32x4){0.f, 0.f, 0.f, 0.f};
    int srow = tid >> 3, soff = (tid & 7) * 8;

    short8 wreg[4], breg[4];
    #pragma unroll
    for (int p = 0; p < 4; p++) {
        wreg[p] = *(const short8*)&Wp[(size_t)(o0 + srow + p * 32) * 512 + soff];
        breg[p] = *(const short8*)&Aw[((size_t)(b * 2048) + t0 + srow + p * 32) * 512 + soff];
    }
    for (int t = 0; t < 8; ++t) {
        int cur = t & 1;
        #pragma unroll
        for (int p = 0; p < 4; p++) {
            *(short8*)&Ws[cur][srow + p * 32][soff] = wreg[p];
            *(short8*)&Bs[cur][srow + p * 32][soff] = breg[p];
        }
        if (t < 7) {
            int k1 = (t + 1) * 64;
            #pragma unroll
            for (int p = 0; p < 4; p++) {
                wreg[p] = *(const short8*)&Wp[(size_t)(o0 + srow + p * 32) * 512 + k1 + soff];
                breg[p] = *(const short8*)&Aw[((size_t)(b * 2048) + t0 + srow + p * 32) * 512 + k1 + soff];
            }
        }
        lds_barrier();
        for (int kk = 0; kk < 64; kk += 32) {
            int kb = kk + lr * 8;
            short8 af[4], bfv[4];
            for (int m = 0; m < 4; m++) af[m]  = *(const short8*)&Ws[cur][wr + m * 16 + lc][kb];
            for (int n = 0; n < 4; n++) bfv[n] = *(const short8*)&Bs[cur][wc + n * 16 + lc][kb];
            for (int m = 0; m < 4; m++)
                for (int n = 0; n < 4; n++)
                    acc[m][n] = __builtin_amdgcn_mfma_f32_16x16x32_bf16(af[m], bfv[n], acc[m][n], 0, 0, 0);
        }
        __builtin_amdgcn_s_barrier();
    }
    for (int m = 0; m < 4; m++)
        for (int n = 0; n < 4; n++)
            for (int r = 0; r < 4; r++) {
                int o = o0 + wr + m * 16 + lr * 4 + r;
                int t = t0 + wc + n * 16 + lc;
                size_t idx = ((size_t)(b * 512) + o) * 2048 + t;
                out[idx] = x[idx] + acc[m][n][r] + proj_b[o];
            }
}

extern "C" void kernel_launch(void* const* d_in, const int* in_sizes, int n_in,
                              void* d_out, int out_size, void* d_ws, size_t ws_size,
                              hipStream_t stream) {
    const float* x      = (const float*)d_in[0];
    const float* qkv_w  = (const float*)d_in[1];
    const float* qkv_b  = (const float*)d_in[2];
    const float* proj_w = (const float*)d_in[3];
    const float* proj_b = (const float*)d_in[4];
    float* out = (float*)d_out;

    unsigned short* ws = (unsigned short*)d_ws;
    unsigned short* Wq = ws;                                   // 1536*512
    unsigned short* Wp = Wq + (size_t)1536 * 512;              // 512*512
    unsigned short* Xt = Wp + (size_t)512 * 512;               // 8*2048*512
    unsigned short* Qw = Xt + (size_t)8 * 2048 * 512;          // 32*2048*128
    unsigned short* Kw = Qw + (size_t)32 * 2048 * 128;
    unsigned short* Vw = Kw + (size_t)32 * 2048 * 128;
    unsigned short* Aw = Vw + (size_t)32 * 2048 * 128;         // 8*2048*512
    unsigned short* Opp = Aw + (size_t)8 * 2048 * 512;         // 2*32*2048*128
    float* Ml = (float*)(Opp + (size_t)2 * 32 * 2048 * 128);   // 2*32*2048*2 f32

    transpose_kernel<<<dim3(32, 8, 8), dim3(256), 0, stream>>>(x, Xt, qkv_w, proj_w, Wq, Wp);
    gemm_qkv_kernel<0><<<dim3(16, 8, 8), dim3(256), 0, stream>>>(Wq, Xt, qkv_b, Qw, Kw, Vw);
    gemm_qkv_kernel<1><<<dim3(16, 4, 8), dim3(256), 0, stream>>>(Wq, Xt, qkv_b, Qw, Kw, Vw);
    attn_kernel<<<dim3(1024), dim3(256), 0, stream>>>(Qw, Kw, Vw, Opp, Ml);
    combine_kernel<<<dim3(4096), dim3(256), 0, stream>>>(Opp, Ml, Aw);
    gemm_proj_kernel<<<dim3(16, 4, 8), dim3(256), 0, stream>>>(Wp, Aw, proj_b, x, out);
}

// Round 19
// 160.914 us; speedup vs baseline: 1.9625x; 1.9625x over previous
//
#include <hip/hip_runtime.h>

#define DEV static __device__ __forceinline__

typedef __attribute__((ext_vector_type(8))) short short8;
typedef __attribute__((ext_vector_type(4))) float f32x4;
typedef __attribute__((ext_vector_type(16))) float f32x16;
typedef __attribute__((ext_vector_type(2))) unsigned int uint2v;

DEV unsigned short f2bf(float f) {
    union { float f; unsigned int u; } v; v.f = f;
    unsigned int u = v.u;
    unsigned int r = (u + 0x7fffu + ((u >> 16) & 1u)) >> 16;
    return (unsigned short)r;
}

// v_cvt_pk_bf16_f32: low short = lo, high short = hi (no builtin on gfx950, m240)
DEV unsigned int cvtpk(float lo, float hi) {
    unsigned int r;
    asm("v_cvt_pk_bf16_f32 %0, %1, %2" : "=v"(r) : "v"(lo), "v"(hi));
    return r;
}

// 2^x on the transcendental pipe
DEV float vexp2(float x) {
    float r;
    asm("v_exp_f32 %0, %1" : "=v"(r) : "v"(x));
    return r;
}

// lane<32 <-> lane>=32 exchange on the VALU pipe (not LDS)
DEV float pl32_max(float v) {
    union { float f; unsigned u; } c; c.f = v;
    uint2v r = __builtin_amdgcn_permlane32_swap(c.u, c.u, false, false);
    union { unsigned u; float f; } a, b; a.u = r[0]; b.u = r[1];
    return fmaxf(a.f, b.f);
}
DEV float pl32_sum(float v) {
    union { float f; unsigned u; } c; c.f = v;
    uint2v r = __builtin_amdgcn_permlane32_swap(c.u, c.u, false, false);
    union { unsigned u; float f; } a, b; a.u = r[0]; b.u = r[1];
    return a.f + b.f;
}

// XOR-swizzled LDS pointer: tile row stride rs shorts (power of 2), byte ^= (row&7)<<4
DEV unsigned short* swp(unsigned short* base, int row, int col, int rs) {
    int a = ((row * rs + col) << 1) ^ ((row & 7) << 4);
    return (unsigned short*)((char*)base + a);
}

// barrier that does NOT drain vmcnt: LDS-write visibility only.
// In-flight global prefetch loads cross it and complete under compute.
DEV void lds_barrier() {
    asm volatile("s_waitcnt lgkmcnt(0)" ::: "memory");
    __builtin_amdgcn_s_barrier();
}

// async global->LDS, 16B/lane. Linear LDS dest (base + lane*16); source address
// carries the chunk^row involution so swizzled ds_read (swp) sees correct data.
DEV void gload16(const void* g, void* l) {
    __builtin_amdgcn_global_load_lds((const __attribute__((address_space(1))) void*)g,
                                     (__attribute__((address_space(3))) void*)l, 16, 0, 0);
}

// ---------------- kernel 1: transpose + fused weight conversion ----------------
// x [b][512][2048] f32 -> Xt [b][2048][512] bf16; grid-striding weight fp32->bf16
// fused in (saves the standalone prep dispatch; weights independent of x).
__global__ __launch_bounds__(256) void transpose_kernel(const float* __restrict__ x,
                                                        unsigned short* __restrict__ Xt,
                                                        const float* __restrict__ qkv_w,
                                                        const float* __restrict__ proj_w,
                                                        unsigned short* __restrict__ Wq,
                                                        unsigned short* __restrict__ Wp) {
    __shared__ unsigned char lt[64 * 128];
    int b  = blockIdx.z;
    int c0 = blockIdx.y * 64;
    int t0 = blockIdx.x * 64;
    int tid = threadIdx.x;

    // fused prep: 2048 blocks x 256 thr = 524288 threads; Wq 786432, Wp 262144 elems
    {
        int gtid = (((int)blockIdx.z * 8 + (int)blockIdx.y) * 32 + (int)blockIdx.x) * 256 + tid;
        for (int j = gtid; j < 1536 * 512; j += 524288) Wq[j] = f2bf(qkv_w[j]);
        for (int j = gtid; j < 512 * 512;  j += 524288) Wp[j] = f2bf(proj_w[j]);
    }

    int tx = tid & 15, cy0 = tid >> 4;
    for (int p = 0; p < 4; ++p) {
        int cy = cy0 + p * 16;
        const float* src = &x[((size_t)(b * 512 + c0 + cy)) * 2048 + t0 + tx * 4];
        f32x4 v = *(const f32x4*)src;
        unsigned long long pk = (unsigned long long)f2bf(v[0])
                              | ((unsigned long long)f2bf(v[1]) << 16)
                              | ((unsigned long long)f2bf(v[2]) << 32)
                              | ((unsigned long long)f2bf(v[3]) << 48);
        int addr = (cy * 128 + tx * 8) ^ ((cy & 7) << 4);
        *(unsigned long long*)(lt + addr) = pk;
    }
    __syncthreads();
    int c16 = (tid & 3) * 16, tr = tid >> 2;
    unsigned short buf[16];
    for (int i = 0; i < 16; ++i) {
        int c = c16 + i;
        int addr = (c * 128 + tr * 2) ^ ((c & 7) << 4);
        buf[i] = *(unsigned short*)(lt + addr);
    }
    unsigned short* dst = &Xt[((size_t)(b * 2048 + t0 + tr)) * 512 + c0 + c16];
    *(short8*)dst       = *(short8*)&buf[0];
    *(short8*)(dst + 8) = *(short8*)&buf[8];
}

// ---------------- kernel 2: QKV GEMM v2 (TEMPLATED orient — mandatory; both the
// runtime-pointer (r7) and runtime-operand-order (r15) merged variants spill) -------
template <int ORIENT>
__global__ __launch_bounds__(256, 2) void gemm_qkv_kernel(
    const unsigned short* __restrict__ Wq,   // [1536][512] bf16
    const unsigned short* __restrict__ Xt,   // [b][2048][512] bf16
    const float* __restrict__ qkv_b,
    unsigned short* __restrict__ Qw,
    unsigned short* __restrict__ Kw,
    unsigned short* __restrict__ Vw) {
    __shared__ unsigned short As[2][128 * 64];
    __shared__ unsigned short Bs[2][128 * 64];
    int b  = blockIdx.z;
    int ot = (ORIENT == 0) ? blockIdx.y : (8 + blockIdx.y);
    int o0 = ot * 128, t0 = blockIdx.x * 128;
    int tid = threadIdx.x, lane = tid & 63, w = tid >> 6;
    int lr = lane >> 4, lc = lane & 15;
    int wr = (w >> 1) * 64, wc = (w & 1) * 64;
    f32x4 acc[4][4];
    for (int m = 0; m < 4; m++)
        for (int n = 0; n < 4; n++) acc[m][n] = (f32x4){0.f, 0.f, 0.f, 0.f};

    int r8 = lane >> 3, ck = lane & 7;
    int sc8 = (ck ^ r8) * 8;

    const unsigned short* Wbase = &Wq[(size_t)o0 * 512];
    const unsigned short* Xbase = &Xt[((size_t)(b * 2048) + t0) * 512];

    #define QKV_STAGE(buf, ks)                                                        \
        _Pragma("unroll")                                                             \
        for (int p = 0; p < 4; p++) {                                                 \
            int rowblk = (w * 4 + p) * 8;                                             \
            gload16(&Wbase[(size_t)(rowblk + r8) * 512 + (ks) * 64 + sc8],            \
                    &As[buf][rowblk * 64]);                                           \
            gload16(&Xbase[(size_t)(rowblk + r8) * 512 + (ks) * 64 + sc8],            \
                    &Bs[buf][rowblk * 64]);                                           \
        }

    QKV_STAGE(0, 0);
    asm volatile("s_waitcnt vmcnt(0)" ::: "memory");
    __builtin_amdgcn_s_barrier();
    for (int t = 0; t < 8; ++t) {
        int cur = t & 1;
        if (t < 7) { QKV_STAGE(cur ^ 1, t + 1); }
        unsigned short* Ab = (unsigned short*)As[cur];
        unsigned short* Bb = (unsigned short*)Bs[cur];
        #pragma unroll
        for (int kk = 0; kk < 64; kk += 32) {
            int kb = kk + lr * 8;
            short8 af[4], bfv[4];
            if (ORIENT == 0) {
                for (int m = 0; m < 4; m++) af[m]  = *(const short8*)swp(Bb, wr + m * 16 + lc, kb, 64);
                for (int n = 0; n < 4; n++) bfv[n] = *(const short8*)swp(Ab, wc + n * 16 + lc, kb, 64);
            } else {
                for (int m = 0; m < 4; m++) af[m]  = *(const short8*)swp(Ab, wr + m * 16 + lc, kb, 64);
                for (int n = 0; n < 4; n++) bfv[n] = *(const short8*)swp(Bb, wc + n * 16 + lc, kb, 64);
            }
            for (int m = 0; m < 4; m++)
                for (int n = 0; n < 4; n++)
                    acc[m][n] = __builtin_amdgcn_mfma_f32_16x16x32_bf16(af[m], bfv[n], acc[m][n], 0, 0, 0);
        }
        asm volatile("s_waitcnt vmcnt(0)" ::: "memory");
        __builtin_amdgcn_s_barrier();
    }
    const float scale_k = 0.29730177875068026f;            // 128^-0.25
    const float scale_q = 0.42891498953885586f;            // 128^-0.25 * log2(e)
    for (int m = 0; m < 4; m++)
        for (int n = 0; n < 4; n++)
            for (int r = 0; r < 4; r++) {
                int row = wr + m * 16 + lr * 4 + r;
                int col = wc + n * 16 + lc;
                float val = acc[m][n][r];
                if (ORIENT == 0) {
                    int t = t0 + row;
                    int o = o0 + col;
                    float sc = (o < 512) ? scale_q : scale_k;
                    val = (val + qkv_b[o]) * sc;
                    if (o < 512) {
                        int h = o >> 7, cc = o & 127;
                        Qw[((size_t)((b * 4 + h) * 2048 + t)) * 128 + cc] = f2bf(val);
                    } else {
                        int oo = o - 512;
                        int h = oo >> 7, cc = oo & 127;
                        Kw[((size_t)((b * 4 + h) * 2048 + t)) * 128 + cc] = f2bf(val);
                    }
                } else {
                    int o = o0 + row;
                    int t = t0 + col;
                    val += qkv_b[o];
                    int oo = o - 1024;
                    int h = oo >> 7, cc = oo & 127;
                    Vw[((size_t)((b * 4 + h) * 128 + cc)) * 2048 + t] = f2bf(val);
                }
            }
}

// ---------------- kernel 3: flash attention v7b (r10/r17-exact — best config) -------
// 256 thr = 4 waves x 32 q; 512 blocks; dbuf K/V, REG prefetch + lds_barrier
// (loads stay in flight across barrier), permlane exchange, defer-max, exp2 domain.
// XCD mapping makes each XCD's 4 bh K/V streams total exactly 4MB = L2 size
// (r18 s-split broke this -> FETCH 24.6MB -> 537MB; locality is load-bearing).
__global__ __launch_bounds__(256, 2) void attn_kernel(
    const unsigned short* __restrict__ Qw,   // [bh][2048][128]
    const unsigned short* __restrict__ Kw,   // [bh][2048][128]
    const unsigned short* __restrict__ Vw,   // [bh][128][2048]
    unsigned short* __restrict__ Aw) {       // [b][2048][512]
    __shared__ unsigned short lds[32768];    // K dbuf 2x8192, V dbuf 2x8192 shorts
    int bid = blockIdx.x;
    int bh = bid & 31;                       // all t-tiles of a bh share bid%8 (XCD)
    int t0 = (bid >> 5) * 128;
    int tid = threadIdx.x, lane = tid & 63, w = tid >> 6;
    int l31 = lane & 31, hi = lane >> 5;
    int qrow = w * 32;

    const unsigned short* Kbase = &Kw[(size_t)bh * 2048 * 128];
    const unsigned short* Vbase = &Vw[(size_t)bh * 128 * 2048];

    short8 qf[8];
    #pragma unroll
    for (int st = 0; st < 8; st++)
        qf[st] = *(const short8*)&Qw[((size_t)bh * 2048 + t0 + qrow + l31) * 128 + st * 16 + hi * 8];

    f32x16 oacc[4];
    #pragma unroll
    for (int ct = 0; ct < 4; ct++)
        #pragma unroll
        for (int i = 0; i < 16; i++) oacc[ct][i] = 0.f;
    float mst = -1e30f, lst = 0.f;

    int kr = tid >> 4, ko = (tid & 15) * 8;  // K stage rows kr + p*16
    int vr = tid >> 3, vo = (tid & 7) * 8;   // V stage rows vr + p*32

    short8 kreg[4], vreg[4];
    #pragma unroll
    for (int p = 0; p < 4; p++)
        kreg[p] = *(const short8*)&Kbase[(size_t)(kr + p * 16) * 128 + ko];
    #pragma unroll
    for (int p = 0; p < 4; p++)
        vreg[p] = *(const short8*)&Vbase[(size_t)(vr + p * 32) * 2048 + vo];

    for (int it = 0; it < 32; ++it) {
        int cur = it & 1;
        unsigned short* Kb = lds + cur * 8192;           // [64 s][128 ch] swz
        unsigned short* Vb = lds + 16384 + cur * 8192;   // [128 c][64 s] swz
        #pragma unroll
        for (int p = 0; p < 4; p++) *(short8*)swp(Kb, kr + p * 16, ko, 128) = kreg[p];
        #pragma unroll
        for (int p = 0; p < 4; p++) *(short8*)swp(Vb, vr + p * 32, vo, 64) = vreg[p];
        if (it + 1 < 32) {
            int s1 = (it + 1) * 64;
            #pragma unroll
            for (int p = 0; p < 4; p++)
                kreg[p] = *(const short8*)&Kbase[(size_t)(s1 + kr + p * 16) * 128 + ko];
            #pragma unroll
            for (int p = 0; p < 4; p++)
                vreg[p] = *(const short8*)&Vbase[(size_t)(vr + p * 32) * 2048 + s1 + vo];
        }
        lds_barrier();   // K/V prefetch stays in flight; LDS writes visible

        // S'[s][q] = K·Q^T
        f32x16 s0, s1v;
        #pragma unroll
        for (int i = 0; i < 16; i++) { s0[i] = 0.f; s1v[i] = 0.f; }
        __builtin_amdgcn_s_setprio(1);
        #pragma unroll
        for (int st = 0; st < 8; st++) {
            short8 k0 = *(const short8*)swp(Kb, l31,      st * 16 + hi * 8, 128);
            short8 k1 = *(const short8*)swp(Kb, 32 + l31, st * 16 + hi * 8, 128);
            s0  = __builtin_amdgcn_mfma_f32_32x32x16_bf16(k0, qf[st], s0, 0, 0, 0);
            s1v = __builtin_amdgcn_mfma_f32_32x32x16_bf16(k1, qf[st], s1v, 0, 0, 0);
        }
        __builtin_amdgcn_s_setprio(0);

        // online softmax (exp2 domain), in-lane + permlane
        float m16[16];
        #pragma unroll
        for (int i = 0; i < 16; i++) m16[i] = fmaxf(s0[i], s1v[i]);
        #pragma unroll
        for (int sdt = 8; sdt > 0; sdt >>= 1)
            #pragma unroll
            for (int i = 0; i < 8; i++)
                if (i < sdt) m16[i] = fmaxf(m16[i], m16[i + sdt]);
        float mx = pl32_max(m16[0]);
        if (!__all(mx <= mst + 11.541560327111707f)) {   // 8 * log2(e)
            float mnew = fmaxf(mst, mx);
            float resc = vexp2(mst - mnew);
            mst = mnew;
            lst *= resc;
            #pragma unroll
            for (int ct = 0; ct < 4; ct++)
                #pragma unroll
                for (int i = 0; i < 16; i++) oacc[ct][i] *= resc;
        }
        float pe[32];
        #pragma unroll
        for (int i = 0; i < 16; i++) pe[i]      = vexp2(s0[i]  - mst);
        #pragma unroll
        for (int i = 0; i < 16; i++) pe[16 + i] = vexp2(s1v[i] - mst);
        float a16[16];
        #pragma unroll
        for (int i = 0; i < 16; i++) a16[i] = pe[i] + pe[16 + i];
        #pragma unroll
        for (int sdt = 8; sdt > 0; sdt >>= 1)
            #pragma unroll
            for (int i = 0; i < 8; i++)
                if (i < sdt) a16[i] = a16[i] + a16[i + sdt];
        lst += pl32_sum(a16[0]);

        // PV B-frags via cvt_pk + permlane32_swap
        short8 pf[4];
        #pragma unroll
        for (int st = 0; st < 4; st++) {
            unsigned X0 = cvtpk(pe[st * 8 + 0], pe[st * 8 + 1]);
            unsigned X1 = cvtpk(pe[st * 8 + 2], pe[st * 8 + 3]);
            unsigned Y0 = cvtpk(pe[st * 8 + 4], pe[st * 8 + 5]);
            unsigned Y1 = cvtpk(pe[st * 8 + 6], pe[st * 8 + 7]);
            uint2v r0 = __builtin_amdgcn_permlane32_swap(X0, Y0, false, false);
            uint2v r1 = __builtin_amdgcn_permlane32_swap(X1, Y1, false, false);
            union { unsigned u[4]; short8 s; } uu;
            uu.u[0] = r0[0];
            uu.u[1] = r1[0];
            uu.u[2] = r0[1];
            uu.u[3] = r1[1];
            pf[st] = uu.s;
        }

        // O[c][q] += V·P
        __builtin_amdgcn_s_setprio(1);
        #pragma unroll
        for (int ct = 0; ct < 4; ct++)
            #pragma unroll
            for (int st = 0; st < 4; st++) {
                short8 va = *(const short8*)swp(Vb, ct * 32 + l31, st * 16 + hi * 8, 64);
                oacc[ct] = __builtin_amdgcn_mfma_f32_32x32x16_bf16(va, pf[st], oacc[ct], 0, 0, 0);
            }
        __builtin_amdgcn_s_setprio(0);
    }

    // epilogue: O/l -> per-wave LDS [32 q][128 c] -> coalesced Aw[t][c]
    __syncthreads();
    unsigned short* ep = lds + w * 4096;
    float invl = 1.f / lst;
    #pragma unroll
    for (int ct = 0; ct < 4; ct++)
        #pragma unroll
        for (int i = 0; i < 8; i++) {
            int c = (2 * i & 3) + 8 * (i >> 1) + 4 * hi + 32 * ct;
            unsigned d = cvtpk(oacc[ct][2 * i] * invl, oacc[ct][2 * i + 1] * invl);
            *(unsigned*)swp(ep, l31, c, 128) = d;
        }
    asm volatile("" ::: "memory");
    int q = lane >> 1, hf = lane & 1;
    int b = bh >> 2, h = bh & 3;
    #pragma unroll
    for (int p = 0; p < 8; p++) {
        short8 v = *(const short8*)swp(ep, q, hf * 64 + p * 8, 128);
        *(short8*)&Aw[((size_t)(b * 2048) + t0 + qrow + q) * 512 + h * 128 + hf * 64 + p * 8] = v;
    }
}

// ---------------- kernel 4: proj GEMM + bias + residual (dbuf + reg prefetch) -------
#define LP 72
__global__ __launch_bounds__(256, 2) void gemm_proj_kernel(
    const unsigned short* __restrict__ Wp,   // [512][512] bf16
    const unsigned short* __restrict__ Aw,   // [b][2048][512] bf16
    const float* __restrict__ proj_b,
    const float* __restrict__ x,             // [b][512][2048] f32
    float* __restrict__ out) {
    __shared__ unsigned short Ws[2][128][LP];
    __shared__ unsigned short Bs[2][128][LP];
    int b  = blockIdx.z;
    int o0 = blockIdx.y * 128, t0 = blockIdx.x * 128;
    int tid = threadIdx.x, lane = tid & 63, w = tid >> 6;
    int lr = lane >> 4, lc = lane & 15;
    int wr = (w >> 1) * 64, wc = (w & 1) * 64;
    f32x4 acc[4][4];
    for (int m = 0; m < 4; m++)
        for (int n = 0; n < 4; n++) acc[m][n] = (f32x4){0.f, 0.f, 0.f, 0.f};
    int srow = tid >> 3, soff = (tid & 7) * 8;

    short8 wreg[4], breg[4];
    #pragma unroll
    for (int p = 0; p < 4; p++) {
        wreg[p] = *(const short8*)&Wp[(size_t)(o0 + srow + p * 32) * 512 + soff];
        breg[p] = *(const short8*)&Aw[((size_t)(b * 2048) + t0 + srow + p * 32) * 512 + soff];
    }
    for (int t = 0; t < 8; ++t) {
        int cur = t & 1;
        #pragma unroll
        for (int p = 0; p < 4; p++) {
            *(short8*)&Ws[cur][srow + p * 32][soff] = wreg[p];
            *(short8*)&Bs[cur][srow + p * 32][soff] = breg[p];
        }
        if (t < 7) {
            int k1 = (t + 1) * 64;
            #pragma unroll
            for (int p = 0; p < 4; p++) {
                wreg[p] = *(const short8*)&Wp[(size_t)(o0 + srow + p * 32) * 512 + k1 + soff];
                breg[p] = *(const short8*)&Aw[((size_t)(b * 2048) + t0 + srow + p * 32) * 512 + k1 + soff];
            }
        }
        lds_barrier();
        for (int kk = 0; kk < 64; kk += 32) {
            int kb = kk + lr * 8;
            short8 af[4], bfv[4];
            for (int m = 0; m < 4; m++) af[m]  = *(const short8*)&Ws[cur][wr + m * 16 + lc][kb];
            for (int n = 0; n < 4; n++) bfv[n] = *(const short8*)&Bs[cur][wc + n * 16 + lc][kb];
            for (int m = 0; m < 4; m++)
                for (int n = 0; n < 4; n++)
                    acc[m][n] = __builtin_amdgcn_mfma_f32_16x16x32_bf16(af[m], bfv[n], acc[m][n], 0, 0, 0);
        }
        __builtin_amdgcn_s_barrier();
    }
    for (int m = 0; m < 4; m++)
        for (int n = 0; n < 4; n++)
            for (int r = 0; r < 4; r++) {
                int o = o0 + wr + m * 16 + lr * 4 + r;
                int t = t0 + wc + n * 16 + lc;
                size_t idx = ((size_t)(b * 512) + o) * 2048 + t;
                out[idx] = x[idx] + acc[m][n][r] + proj_b[o];
            }
}

extern "C" void kernel_launch(void* const* d_in, const int* in_sizes, int n_in,
                              void* d_out, int out_size, void* d_ws, size_t ws_size,
                              hipStream_t stream) {
    const float* x      = (const float*)d_in[0];
    const float* qkv_w  = (const float*)d_in[1];
    const float* qkv_b  = (const float*)d_in[2];
    const float* proj_w = (const float*)d_in[3];
    const float* proj_b = (const float*)d_in[4];
    float* out = (float*)d_out;

    unsigned short* ws = (unsigned short*)d_ws;
    unsigned short* Wq = ws;                                   // 1536*512
    unsigned short* Wp = Wq + (size_t)1536 * 512;              // 512*512
    unsigned short* Xt = Wp + (size_t)512 * 512;               // 8*2048*512
    unsigned short* Qw = Xt + (size_t)8 * 2048 * 512;          // 32*2048*128
    unsigned short* Kw = Qw + (size_t)32 * 2048 * 128;
    unsigned short* Vw = Kw + (size_t)32 * 2048 * 128;
    unsigned short* Aw = Vw + (size_t)32 * 2048 * 128;         // 8*2048*512

    transpose_kernel<<<dim3(32, 8, 8), dim3(256), 0, stream>>>(x, Xt, qkv_w, proj_w, Wq, Wp);
    gemm_qkv_kernel<0><<<dim3(16, 8, 8), dim3(256), 0, stream>>>(Wq, Xt, qkv_b, Qw, Kw, Vw);
    gemm_qkv_kernel<1><<<dim3(16, 4, 8), dim3(256), 0, stream>>>(Wq, Xt, qkv_b, Qw, Kw, Vw);
    attn_kernel<<<dim3(512), dim3(256), 0, stream>>>(Qw, Kw, Vw, Aw);
    gemm_proj_kernel<<<dim3(16, 4, 8), dim3(256), 0, stream>>>(Wp, Aw, proj_b, x, out);
}